// Round 11
// baseline (30.781 us; speedup 1.0000x reference)
//
#include <hip/hip_runtime.h>
#include <cstdint>

// Rule 30, 2 states, r=1, wrap. idx = L + 2C + 4R, table = bits of 30
// reduces to: new = R ^ (C | L).
//
// B=16 rows, W=2048 cells, T=1024 steps, history = T+1 states.
// Output: int32 [B][T+1][W] (reference returns uint8 -> harness int32).
//
// Round-11: FINE-GRAINED TIME-STAGGER (kill the serial head).
//   Model from R6/R8/R10 (all ~29-31us): per-CU write rate is capped at
//   ~26 GB/s (= peak HBM / 256 CUs; the fill kernel shows the same), so
//   dur ~= max_head_chain + 524KB/26GBps. R8/R10 pay a ~7us head (the CU
//   owning the last time-chunk chains ~1000 steps before storing anything).
//   Fix: each block owns FOUR 16-state chunks spaced 256 steps apart.
//   256 blocks = 16 rows x 16 stagger-slots j; block (b,j) seeds at steps
//   j*16 + k*256 (k=0..3). Head <= 240 steps (~1.2us); the 240-step
//   mid-chains between chunks hide under the previous chunk's ~5us store
//   phase (double-buffered LDS). Per-CU bytes unchanged.
//
//   Chain (wave 0 only, proven R5-R10): ghost-zone window, one 32-bit
//   shuffle pair per 16 steps; rule on the 64-bit window is
//   win = (win>>1) ^ (win | (win<<1)) (v_lshlrev_b64/v_lshrrev_b64),
//   middle 32 bits valid for exactly 16 steps.

#define B 16
#define W 2048
#define T_ITERS 1024
#define HIST (T_ITERS + 1)
#define LANES 64
#define CH 16                      // states per chunk (= halo validity)
#define NCH 4                      // chunks per block
#define JSLOTS 16                  // stagger slots per row
#define SPACING (JSLOTS * CH)      // 256 steps between a block's chunks
#define ROW_I4 (W / 4)             // 512 int4 per state row

typedef unsigned long long u64;
typedef int v4i __attribute__((ext_vector_type(4)));

__device__ __forceinline__ void store_nib_nt(v4i* o, unsigned nib) {
    v4i f;
    f.x = (int)(nib & 1u);
    f.y = (int)((nib >> 1) & 1u);
    f.z = (int)((nib >> 2) & 1u);
    f.w = (int)((nib >> 3) & 1u);
    __builtin_nontemporal_store(f, o);   // global_store_dwordx4 ... nt
}

// one 16-step exchange group; if dst != nullptr, record the 16 states
__device__ __forceinline__ unsigned chain16(unsigned m, int l, unsigned* dst) {
    unsigned left  = __shfl(m, (l + LANES - 1) & (LANES - 1));
    unsigned right = __shfl(m, (l + 1) & (LANES - 1));
    // window bit p = cell (32l - 16 + p); bits [16..47] = own cells
    u64 win = ((u64)(left >> 16)) | ((u64)m << 16) | ((u64)right << 48);
    if (dst) {
        #pragma unroll
        for (int j = 0; j < CH; ++j) {
            win = (win >> 1) ^ (win | (win << 1));   // rule 30, 64 bits
            m = (unsigned)(win >> 16);               // valid for j<=15
            dst[j * LANES] = m;                      // 2 lanes/bank: free
        }
    } else {
        #pragma unroll
        for (int j = 0; j < CH; ++j)
            win = (win >> 1) ^ (win | (win << 1));
        m = (unsigned)(win >> 16);
    }
    return m;
}

__global__ __launch_bounds__(256) void ca_stagger(const float* __restrict__ x,
                                                  v4i* __restrict__ out) {
    __shared__ unsigned st[2][CH][LANES];    // double-buffered chunk
    __shared__ unsigned st0[LANES];          // packed t=0 (j==0 only)

    const int blk = blockIdx.x;
    const int b = blk & (B - 1);             // row
    const int j = blk >> 4;                  // stagger slot 0..15
    const int tid = threadIdx.x;
    const int wave = tid >> 6;               // 0..3
    const int l = tid & 63;                  // lane

    unsigned m = 0;
    if (wave == 0) {
        // ---- pack 32 thresholded floats into u32 (bit i = cell 32l+i) ----
        const float4* xv = (const float4*)(x + (size_t)b * W + (size_t)l * 32);
        #pragma unroll
        for (int i = 0; i < 8; ++i) {
            float4 v = xv[i];
            unsigned n = (v.x >= 0.5f ? 1u : 0u) | (v.y >= 0.5f ? 2u : 0u) |
                         (v.z >= 0.5f ? 4u : 0u) | (v.w >= 0.5f ? 8u : 0u);
            m |= n << (4 * i);
        }
        if (j == 0) st0[l] = m;

        // ---- head: j groups of 16 steps (<= 240 steps ~ 1.2us) ----
        for (int g = 0; g < j; ++g) m = chain16(m, l, nullptr);
        // ---- emit chunk 0 (seed step j*16) into buffer 0 ----
        m = chain16(m, l, &st[0][0][l]);
    }
    __syncthreads();

    // ---- t=0 row (j==0 blocks): 512 int4 across 256 threads ----
    if (j == 0) {
        v4i* o = out + ((size_t)b * HIST) * ROW_I4;
        #pragma unroll
        for (int h = 0; h < 2; ++h) {
            int c = tid + 256 * h;
            unsigned u = st0[c >> 3];
            store_nib_nt(o + c, (u >> ((c & 7) * 4)) & 0xFu);
        }
    }

    // ---- chunks: wave 0 chains 240 steps + emits k+1 || all store k ----
    for (int k = 0; k < NCH; ++k) {
        if (wave == 0 && k < NCH - 1) {
            // from state (seed_k + 16) to seed_{k+1}: 15 groups, no store
            for (int g = 0; g < JSLOTS - 1; ++g) m = chain16(m, l, nullptr);
            m = chain16(m, l, &st[(k + 1) & 1][0][l]);   // emit chunk k+1
        }
        // store chunk k: 16 states, 4 per wave; NT int4 wave-stores.
        // nibble c of a packed row: word c>>3 = (l>>3)+8i, shift (l&7)*4.
        const size_t t0 = (size_t)(j * CH + k * SPACING + 1);
        #pragma unroll
        for (int jj = 0; jj < 4; ++jj) {
            const int jr = wave * 4 + jj;
            v4i* o = out + ((size_t)b * HIST + t0 + jr) * ROW_I4;
            #pragma unroll
            for (int i = 0; i < 8; ++i) {
                unsigned u = st[k & 1][jr][(l >> 3) + 8 * i];
                store_nib_nt(o + l + 64 * i, (u >> ((l & 7) * 4)) & 0xFu);
            }
        }
        __syncthreads();   // st[k&1] fully read before overwrite at k+2;
                           // st[(k+1)&1] fully written before reads at k+1
    }
}

extern "C" void kernel_launch(void* const* d_in, const int* in_sizes, int n_in,
                              void* d_out, int out_size, void* d_ws, size_t ws_size,
                              hipStream_t stream) {
    const float* x = (const float*)d_in[0];
    // 256 independent blocks (1 per CU, 4 waves each); no workspace needed.
    ca_stagger<<<B * JSLOTS, 256, 0, stream>>>(x, (v4i*)d_out);
}

// Round 12
// 27.354 us; speedup vs baseline: 1.1253x; 1.1253x over previous
//
#include <hip/hip_runtime.h>
#include <cstdint>

// Rule 30, 2 states, r=1, wrap. idx = L + 2C + 4R, table = bits of 30
// reduces to: new = R ^ (C | L).
//
// B=16 rows, W=2048 cells, T=1024 steps, history = T+1 states.
// Output: int32 [B][T+1][W] (reference returns uint8 -> harness int32).
//
// Round-12 = round-8 structure (best, 29.4us) with PLAIN stores (NT removed).
//   R6/R8/R10/R11 all plateau at 29-31us = ~4.6 TB/s NT-store rate, while
//   the harness's fillBufferAligned (PLAIN stores, ~3 waves/CU) sustains
//   6.5-6.9 TB/s on the same buffer each replay -> plain stores are not
//   inherently slow; the R5->R6 "L2 churn" inference came from a structure
//   with chain/store interleaved in one wave. Also: the 134-MB output fits
//   in the 256-MiB Infinity Cache; plain write-back stores may complete
//   into L3 inside the timed window (NT structurally cannot).
//   Discriminator: (a) L3 absorb -> 20-24us & our WRITE_SIZE < 131MB;
//   (b) flat ~29 -> fixed transient, revert to NT & declare;
//   (c) 38-45us -> churn real, NT vindicated, revert & declare.
//
// Structure (R8, proven): 1024 blocks = 16 rows x 64 chunks, 256 threads.
// Wave 0 re-runs row b's bit-packed chain from t=0 (ghost-zone window:
// one 32-bit shuffle pair per 16 steps; rule on the 64-bit window is
// win = (win>>1) ^ (win | (win<<1)); middle 32 bits valid 16 steps),
// parks its 16-state chunk in LDS; barrier; all 4 waves expand 4 states
// each as contiguous int4 wave-stores.

#define B 16
#define W 2048
#define T_ITERS 1024
#define HIST (T_ITERS + 1)
#define LANES 64
#define K_STEPS 16
#define RBLKS (T_ITERS / K_STEPS)      // 64 chunks
#define ROW_I4 (W / 4)                 // 512 int4 per state row

typedef unsigned long long u64;
typedef int v4i __attribute__((ext_vector_type(4)));

__device__ __forceinline__ void store_nib(v4i* o, unsigned nib) {
    v4i f;
    f.x = (int)(nib & 1u);
    f.y = (int)((nib >> 1) & 1u);
    f.z = (int)((nib >> 2) & 1u);
    f.w = (int)((nib >> 3) & 1u);
    *o = f;                              // plain global_store_dwordx4
}

__global__ __launch_bounds__(256) void ca_redundant(const float* __restrict__ x,
                                                    v4i* __restrict__ out) {
    __shared__ unsigned st[K_STEPS][LANES];   // chunk's 16 packed states
    __shared__ unsigned st0[LANES];           // packed t=0 (r==0 only)

    const int blk = blockIdx.x;
    const int b = blk & (B - 1);              // row
    const int r = blk >> 4;                   // time-chunk 0..63
    const int tid = threadIdx.x;
    const int wave = tid >> 6;                // 0..3
    const int l = tid & 63;                   // lane

    if (wave == 0) {
        // ---- pack 32 thresholded floats into a u32 (bit i = cell 32l+i) ----
        const float4* xv = (const float4*)(x + (size_t)b * W + (size_t)l * 32);
        unsigned m = 0;
        #pragma unroll
        for (int i = 0; i < 8; ++i) {
            float4 v = xv[i];
            unsigned n = (v.x >= 0.5f ? 1u : 0u) | (v.y >= 0.5f ? 2u : 0u) |
                         (v.z >= 0.5f ? 4u : 0u) | (v.w >= 0.5f ? 8u : 0u);
            m |= n << (4 * i);
        }
        if (r == 0) st0[l] = m;

        // ---- chain: r+1 exchange groups of 16 steps; save only group r ----
        for (int g = 0; g <= r; ++g) {
            unsigned left  = __shfl(m, (l + LANES - 1) & (LANES - 1));
            unsigned right = __shfl(m, (l + 1) & (LANES - 1));
            // window bit p = cell (32l - 16 + p); bits [16..47] = own cells
            u64 win = ((u64)(left >> 16)) | ((u64)m << 16) | ((u64)right << 48);
            if (g < r) {
                #pragma unroll
                for (int j = 0; j < K_STEPS; ++j)
                    win = (win >> 1) ^ (win | (win << 1));   // rule 30, 64 bits
                m = (unsigned)(win >> 16);                   // valid at 16 steps
            } else {
                #pragma unroll
                for (int j = 0; j < K_STEPS; ++j) {
                    win = (win >> 1) ^ (win | (win << 1));
                    m = (unsigned)(win >> 16);               // valid for j<=15
                    st[j][l] = m;                            // 2 lanes/bank: free
                }
            }
        }
    }
    __syncthreads();

    // ---- expand: all 4 waves, 4 states each; contiguous int4 stores ----
    // nibble c of a packed row: word c>>3 = (l>>3)+8i, shift (l&7)*4.
    // LDS reads: 8-lane broadcast per word, 8 words across 8 banks -> clean.
    if (r == 0) {
        // t = 0 row: 512 int4 split across all 256 threads (2 each)
        v4i* o = out + ((size_t)b * HIST) * ROW_I4;
        #pragma unroll
        for (int h = 0; h < 2; ++h) {
            int c = tid + 256 * h;
            unsigned u = st0[c >> 3];
            store_nib(o + c, (u >> ((c & 7) * 4)) & 0xFu);
        }
    }
    #pragma unroll
    for (int jj = 0; jj < 4; ++jj) {
        const int j = wave * 4 + jj;
        v4i* o = out + ((size_t)b * HIST + (size_t)(r * K_STEPS + 1 + j)) * ROW_I4;
        #pragma unroll
        for (int i = 0; i < 8; ++i) {
            unsigned u = st[j][(l >> 3) + 8 * i];
            store_nib(o + l + 64 * i, (u >> ((l & 7) * 4)) & 0xFu);
        }
    }
}

extern "C" void kernel_launch(void* const* d_in, const int* in_sizes, int n_in,
                              void* d_out, int out_size, void* d_ws, size_t ws_size,
                              hipStream_t stream) {
    const float* x = (const float*)d_in[0];
    // 1024 independent blocks (4 waves each); no workspace needed.
    ca_redundant<<<B * RBLKS, 256, 0, stream>>>(x, (v4i*)d_out);
}